// Round 5
// baseline (4497.099 us; speedup 1.0000x reference)
//
#include <hip/hip_runtime.h>
#include <cstddef>
#include <cstdint>

#define Bn 256
#define Pn 192
#define Mn 321
#define Mp 336     // padded channel dim (multiple of 16); Mp/8 = 42 uint4 per row
#define HIDCn 128
#define HIDRn 128
#define HIDSn 8
#define CKn 6
#define SKIPn 24
#define HWn 24
#define Ln 187   // Pn - CKn + 1
#define PTn 7

typedef _Float16 f16;
typedef f16 f16x2 __attribute__((ext_vector_type(2)));
typedef f16 f16x8 __attribute__((ext_vector_type(8)));
typedef float f32x16 __attribute__((ext_vector_type(16)));

__device__ __forceinline__ float sigmf(float x) { return 1.f / (1.f + expf(-x)); }

// ================= tree weight repack + fp16 cast =================
// in: tree_w (NB,4,M,M,K) -> slabs: [slot][k][cib21][co384][ci16] f16
__global__ __launch_bounds__(256) void repack_w(const float* __restrict__ w, f16* __restrict__ out,
                                                int K, int c0, int c1, int c2) {
  int s = blockIdx.z;
  int n = s >> 2, jj = s & 3;
  int blk = c0 + c1 * n + c2 * (n >> 1);
  int kcib = blockIdx.y;
  int k = kcib / 21, cib = kcib - 21 * k;
  int idx = blockIdx.x * 256 + threadIdx.x;  // [0, 6144)
  int co = idx >> 4, cc = idx & 15;
  int ci = cib * 16 + cc;
  f16 val = (f16)0.f;
  if (co < Mn && ci < Mn)
    val = (f16)w[(((size_t)(blk * 4 + jj) * Mn + co) * Mn + ci) * K + k];
  out[(((size_t)s * K + k) * 21 + cib) * 6144 + idx] = val;
}

// ================= conv2d weight repack: (128,1,6,321) -> [k][cib21][co128][ci16] f16 =================
__global__ __launch_bounds__(256) void repack_c1w(const float* __restrict__ w, f16* __restrict__ out) {
  int z = blockIdx.y;                        // 0..125
  int idx = blockIdx.x * 256 + threadIdx.x;  // 0..2047
  int k = z / 21, cib = z - 21 * k;
  int co = idx >> 4, cc = idx & 15;
  int ci = cib * 16 + cc;
  f16 v = (f16)0.f;
  if (ci < Mn) v = (f16)w[((size_t)co * CKn + k) * Mn + ci];
  out[(size_t)z * 2048 + idx] = v;
}

// ================= gru1 wih repack: (384,128) -> [cib8][g384][ci16] f16 =================
__global__ __launch_bounds__(256) void repack_wih(const float* __restrict__ wih, f16* __restrict__ out) {
  int idx = blockIdx.x * 256 + threadIdx.x;  // 0..49151
  int cib = idx / 6144;
  int rem = idx - cib * 6144;
  int g = rem >> 4, cc = idx & 15;
  out[idx] = (f16)wih[(size_t)g * 128 + cib * 16 + cc];
}

// ================= deinterleave -> e/o planes (single fp16) =================
__global__ __launch_bounds__(256) void deint_k(const float* __restrict__ x32,
                                               const f16* __restrict__ parent, int Thp,
                                               f16* __restrict__ o, int Th) {
  int b = blockIdx.x, t = blockIdx.y, z = blockIdx.z;
  int c = z >> 1, eo = z & 1;
  int srow = 2 * t + eo;
  size_t ooff = (((size_t)z * Bn + b) * Th + t) * Mp;
  if (x32) {
    const float* xp = x32 + ((size_t)b * Pn + srow) * Mn;
    for (int m = threadIdx.x; m < Mp; m += 256)
      o[ooff + m] = (m < Mn) ? (f16)xp[m] : (f16)0.f;
  } else {
    const uint32_t* ip = (const uint32_t*)(parent + (((size_t)c * Bn + b) * Thp + srow) * Mp);
    uint32_t* op = (uint32_t*)(o + ooff);
    for (int i = threadIdx.x; i < Mp / 2; i += 256) op[i] = ip[i];
  }
}

// ================= MFMA branch conv v2: double-buffered, 1 barrier/step =================
// block 256 thr / 4 waves: wm=batch(2), wc=co-half(192 each, 6 ct). m-tile 2b x 32t.
// MK 0: leaky   MK 1: out = src*exp(tanh(v))   MK 2: out = src +/- tanh(v) (by z&1)
template <int K, int MK>
__global__ __launch_bounds__(256, 3) void conv_mfma(
    const f16* __restrict__ inz, long in_zs, int Tin,
    const f16* __restrict__ Wb, int wc0, int wc1, int wc2, int wjoff,
    const float* __restrict__ biasb,
    const f16* __restrict__ srcz, long src_zs,
    f16* __restrict__ outz, long out_zs, int Tout) {
  constexpr int PADL = (K == 5) ? 3 : 0;
  constexpr int NIT = 21 * K;
  __shared__ __align__(16) f16 sX[2][2][40][24];
  __shared__ __align__(16) f16 sW[2][384][24];
  int z = blockIdx.z;
  int nnode = z >> 1, j = z & 1;
  int blk = wc0 + wc1 * nnode + wc2 * (nnode >> 1);
  int slot = nnode * 4 + wjoff + j;
  const uint4* inu = (const uint4*)(inz + (size_t)z * in_zs);
  const uint4* wsl = (const uint4*)(Wb + (size_t)slot * (K * 21 * 6144));
  const float* bias = biasb + (size_t)(blk * 4 + wjoff + j) * Mn;
  int b0 = blockIdx.x * 2;
  int t0 = blockIdx.y * 32;
  int tid = threadIdx.x;
  int lane = tid & 63;
  int wv = tid >> 6;
  int wm = wv & 1, wc = wv >> 1;

  f32x16 acc[6];
#pragma unroll
  for (int i = 0; i < 6; ++i)
#pragma unroll
    for (int q = 0; q < 16; ++q) acc[i][q] = 0.f;

  uint4 wr4[3];
  uint4 xr4;
  int xbl = tid / 80, xtt = (tid >> 1) % 40, xh = tid & 1;  // X-stage role (tid<160)

  auto loadW = [&](int cb, int k) {
    const uint4* wp = wsl + (size_t)(k * 21 + cb) * 768;
#pragma unroll
    for (int q = 0; q < 3; ++q) wr4[q] = wp[tid + q * 256];
  };
  auto loadX = [&](int cb) {
    if (tid < 160) {
      int ts = min(max(t0 + xtt - PADL, 0), Tin - 1);
      xr4 = inu[((size_t)(b0 + xbl) * Tin + ts) * 42 + cb * 2 + xh];
    }
  };

  loadX(0);
  loadW(0, 0);
  int cb = 0, k = 0;
#pragma unroll 1
  for (int it = 0; it < NIT; ++it) {
    int xb = cb & 1, wbuf = it & 1;
    if (k == 0 && tid < 160) *(uint4*)&sX[xb][xbl][xtt][xh * 8] = xr4;
#pragma unroll
    for (int q = 0; q < 3; ++q) {
      int idx = tid + q * 256;
      *(uint4*)&sW[wbuf][idx >> 1][(idx & 1) * 8] = wr4[q];
    }
    __syncthreads();
    int kn = k + 1, cbn = cb;
    if (kn == K) { kn = 0; ++cbn; }
    if (it + 1 < NIT) {
      loadW(cbn, kn);
      if (kn == 0) loadX(cbn);
    }
    f16x8 ah = *(const f16x8*)&sX[xb][wm][(lane & 31) + k][(lane >> 5) * 8];
#pragma unroll
    for (int ct = 0; ct < 6; ++ct) {
      f16x8 bw = *(const f16x8*)&sW[wbuf][wc * 192 + ct * 32 + (lane & 31)][(lane >> 5) * 8];
      acc[ct] = __builtin_amdgcn_mfma_f32_32x32x16_f16(ah, bw, acc[ct], 0, 0, 0);
    }
    cb = cbn;
    k = kn;
  }
  // epilogue
  f16* o = outz + (size_t)z * out_zs;
  const f16* s = srcz ? srcz + (size_t)(z ^ 1) * src_zs : nullptr;
#pragma unroll
  for (int ct = 0; ct < 6; ++ct) {
    int co = wc * 192 + ct * 32 + (lane & 31);
    if (co >= Mp) continue;
    float bb = (co < Mn) ? bias[co] : 0.f;
#pragma unroll
    for (int r = 0; r < 16; ++r) {
      int row = (r & 3) + 8 * (r >> 2) + 4 * (lane >> 5);
      int t = t0 + row;
      if (t >= Tout) continue;
      size_t oo = (((size_t)(b0 + wm)) * Tout + t) * Mp + co;
      float res;
      if (co >= Mn) {
        res = 0.f;
      } else {
        float v = acc[ct][r] + bb;
        if constexpr (MK == 0) {
          res = v > 0.f ? v : 0.01f * v;
        } else {
          float sv = (float)s[oo];
          float th = tanhf(v);
          if constexpr (MK == 1) res = sv * expf(th);
          else res = (j == 0) ? sv + th : sv - th;
        }
      }
      o[oo] = (f16)res;
    }
  }
}

// ================= final combine: XRh = f16(x + interleave(leaves)) =================
__global__ __launch_bounds__(256) void combine_k(const float* __restrict__ x, const f16* __restrict__ lv,
                                                 f16* __restrict__ XRh) {
  int b = blockIdx.x, p = blockIdx.y;
  int c = ((p & 1) << 2) | (p & 2) | ((p >> 2) & 1);
  int row = p >> 3;
  size_t li = (((size_t)c * Bn + b) * 24 + row) * Mp;
  const float* xp = x + ((size_t)b * Pn + p) * Mn;
  f16* op = XRh + ((size_t)b * Pn + p) * Mp;
  for (int m = threadIdx.x; m < Mp; m += 256)
    op[m] = (m < Mn) ? (f16)(xp[m] + (float)lv[li + m]) : (f16)0.f;
}

// ================= conv2d MFMA: XRh (B,P,Mp) -> Cc f16 (L,B,128), relu =================
// block 256/4 waves: wm=batch(2), wc=co-half(64 each, 2 ct)
__global__ __launch_bounds__(256, 3) void conv2d_mfma(const f16* __restrict__ XRh,
                                                      const f16* __restrict__ W2,
                                                      const float* __restrict__ bias,
                                                      f16* __restrict__ Cc) {
  constexpr int NIT = 21 * CKn;  // 126
  __shared__ __align__(16) f16 sX[2][2][40][24];
  __shared__ __align__(16) f16 sW[2][128][24];
  int b0 = blockIdx.x * 2;
  int t0 = blockIdx.y * 32;
  int tid = threadIdx.x;
  int lane = tid & 63;
  int wv = tid >> 6;
  int wm = wv & 1, wc = wv >> 1;
  const uint4* inu = (const uint4*)XRh;
  const uint4* wsl = (const uint4*)W2;

  f32x16 acc[2];
#pragma unroll
  for (int i = 0; i < 2; ++i)
#pragma unroll
    for (int q = 0; q < 16; ++q) acc[i][q] = 0.f;

  uint4 wr4, xr4;
  int xbl = tid / 80, xtt = (tid >> 1) % 40, xh = tid & 1;

  auto loadW = [&](int cb, int k) { wr4 = wsl[(size_t)(k * 21 + cb) * 256 + tid]; };
  auto loadX = [&](int cb) {
    if (tid < 160) {
      int ts = min(t0 + xtt, Pn - 1);
      xr4 = inu[((size_t)(b0 + xbl) * Pn + ts) * 42 + cb * 2 + xh];
    }
  };

  loadX(0);
  loadW(0, 0);
  int cb = 0, k = 0;
#pragma unroll 1
  for (int it = 0; it < NIT; ++it) {
    int xb = cb & 1, wbuf = it & 1;
    if (k == 0 && tid < 160) *(uint4*)&sX[xb][xbl][xtt][xh * 8] = xr4;
    *(uint4*)&sW[wbuf][tid >> 1][(tid & 1) * 8] = wr4;
    __syncthreads();
    int kn = k + 1, cbn = cb;
    if (kn == CKn) { kn = 0; ++cbn; }
    if (it + 1 < NIT) {
      loadW(cbn, kn);
      if (kn == 0) loadX(cbn);
    }
    f16x8 ah = *(const f16x8*)&sX[xb][wm][(lane & 31) + k][(lane >> 5) * 8];
#pragma unroll
    for (int ct = 0; ct < 2; ++ct) {
      f16x8 bw = *(const f16x8*)&sW[wbuf][wc * 64 + ct * 32 + (lane & 31)][(lane >> 5) * 8];
      acc[ct] = __builtin_amdgcn_mfma_f32_32x32x16_f16(ah, bw, acc[ct], 0, 0, 0);
    }
    cb = cbn;
    k = kn;
  }
#pragma unroll
  for (int ct = 0; ct < 2; ++ct) {
    int co = wc * 64 + ct * 32 + (lane & 31);
    float bb = bias[co];
#pragma unroll
    for (int r = 0; r < 16; ++r) {
      int row = (r & 3) + 8 * (r >> 2) + 4 * (lane >> 5);
      int l = t0 + row;
      if (l < Ln) {
        float v = acc[ct][r] + bb;
        Cc[((size_t)l * Bn + (b0 + wm)) * HIDCn + co] = (f16)(v > 0.f ? v : 0.f);
      }
    }
  }
}

// ================= GRU1 input GEMM (MFMA): Cc f16 (47872x128) @ wih^T -> gi fp32 =================
__global__ __launch_bounds__(256, 2) void gemm_gi_mfma(const f16* __restrict__ Cc,
                                                       const f16* __restrict__ Wih,
                                                       const float* __restrict__ bih,
                                                       float* __restrict__ gi) {
  __shared__ __align__(16) f16 sA[2][64][24];
  __shared__ __align__(16) f16 sW[2][384][24];
  int r0 = blockIdx.x * 64;
  int tid = threadIdx.x;
  int lane = tid & 63;
  int wv = tid >> 6;
  int wm = wv & 1, wc = wv >> 1;
  const uint4* au = (const uint4*)Cc;
  const uint4* wu = (const uint4*)Wih;

  f32x16 acc[6];
#pragma unroll
  for (int i = 0; i < 6; ++i)
#pragma unroll
    for (int q = 0; q < 16; ++q) acc[i][q] = 0.f;

  uint4 wr4[3], ar4;
  auto loadW = [&](int cb) {
    const uint4* wp = wu + (size_t)cb * 768;
#pragma unroll
    for (int q = 0; q < 3; ++q) wr4[q] = wp[tid + q * 256];
  };
  auto loadA = [&](int cb) {
    if (tid < 128) ar4 = au[((size_t)(r0 + (tid >> 1))) * 16 + cb * 2 + (tid & 1)];
  };

  loadA(0);
  loadW(0);
#pragma unroll 1
  for (int it = 0; it < 8; ++it) {
    int buf = it & 1;
    if (tid < 128) *(uint4*)&sA[buf][tid >> 1][(tid & 1) * 8] = ar4;
#pragma unroll
    for (int q = 0; q < 3; ++q) {
      int idx = tid + q * 256;
      *(uint4*)&sW[buf][idx >> 1][(idx & 1) * 8] = wr4[q];
    }
    __syncthreads();
    if (it + 1 < 8) { loadA(it + 1); loadW(it + 1); }
    f16x8 ah = *(const f16x8*)&sA[buf][wm * 32 + (lane & 31)][(lane >> 5) * 8];
#pragma unroll
    for (int ct = 0; ct < 6; ++ct) {
      f16x8 bw = *(const f16x8*)&sW[buf][wc * 192 + ct * 32 + (lane & 31)][(lane >> 5) * 8];
      acc[ct] = __builtin_amdgcn_mfma_f32_32x32x16_f16(ah, bw, acc[ct], 0, 0, 0);
    }
  }
#pragma unroll
  for (int ct = 0; ct < 6; ++ct) {
    int co = wc * 192 + ct * 32 + (lane & 31);
    float bb = bih[co];
#pragma unroll
    for (int r = 0; r < 16; ++r) {
      int row = (r & 3) + 8 * (r >> 2) + 4 * (lane >> 5);
      gi[(size_t)(r0 + wm * 32 + row) * 384 + co] = acc[ct][r] + bb;
    }
  }
}

// ================= GRU1 recurrent v2: 1 batch/block, whh in registers =================
__global__ __launch_bounds__(384) void gru1_k(const float* __restrict__ gi, const float* __restrict__ whh,
                                              const float* __restrict__ bhh, float* __restrict__ hout) {
  __shared__ __align__(16) uint32_t swc[64][68];
  __shared__ float hf[128];
  __shared__ __align__(16) uint32_t hp[64];
  __shared__ float ghb[384];
  int n = blockIdx.x;
  int tid = threadIdx.x;
  int myc = tid >> 6, lr = tid & 63;
  uint4 wreg[16];
  for (int c = 0; c < 6; ++c) {
    for (int p = tid; p < 4096; p += 384) {
      int row = p >> 6, cp = p & 63;
      const float* wr = whh + ((size_t)(c * 64 + row)) * 128 + 2 * cp;
      f16 h0 = (f16)wr[0], h1 = (f16)wr[1];
      uint32_t u = (uint32_t)__builtin_bit_cast(unsigned short, h0) |
                   ((uint32_t)__builtin_bit_cast(unsigned short, h1) << 16);
      swc[row][cp] = u;
    }
    __syncthreads();
    if (myc == c) {
#pragma unroll
      for (int q = 0; q < 16; ++q) wreg[q] = *(const uint4*)&swc[lr][q * 4];
    }
    __syncthreads();
  }
  if (tid < 128) hf[tid] = 0.f;
  if (tid < 64) hp[tid] = 0u;
  float bias_g = bhh[tid];
  __syncthreads();
  for (int t = 0; t < Ln; ++t) {
    float grv = 0.f, gzv = 0.f, gnv = 0.f, hprev = 0.f;
    if (tid < 128) {
      const float* gp = gi + ((size_t)t * Bn + n) * 384;
      grv = gp[tid]; gzv = gp[128 + tid]; gnv = gp[256 + tid];
      hprev = hf[tid];
    }
    float acc = bias_g;
#pragma unroll
    for (int q = 0; q < 16; ++q) {
      uint4 h4 = *(const uint4*)&hp[q * 4];
      uint4 w4 = wreg[q];
      const uint32_t hu[4] = {h4.x, h4.y, h4.z, h4.w};
      const uint32_t wu2[4] = {w4.x, w4.y, w4.z, w4.w};
#pragma unroll
      for (int e = 0; e < 4; ++e) {
        f16x2 wvp = __builtin_bit_cast(f16x2, wu2[e]);
        f16x2 hvp = __builtin_bit_cast(f16x2, hu[e]);
        acc = fmaf((float)wvp.x, (float)hvp.x, acc);
        acc = fmaf((float)wvp.y, (float)hvp.y, acc);
      }
    }
    ghb[tid] = acc;
    __syncthreads();
    if (tid < 128) {
      float rg = sigmf(grv + ghb[tid]);
      float zg = sigmf(gzv + ghb[128 + tid]);
      float ng = tanhf(gnv + rg * ghb[256 + tid]);
      float hnew = (1.f - zg) * ng + zg * hprev;
      hf[tid] = hnew;
      float other = __shfl_xor(hnew, 1, 64);
      if (!(tid & 1)) {
        f16 a = (f16)hnew, bq = (f16)other;
        hp[tid >> 1] = (uint32_t)__builtin_bit_cast(unsigned short, a) |
                       ((uint32_t)__builtin_bit_cast(unsigned short, bq) << 16);
      }
    }
    __syncthreads();
  }
  if (tid < 128) hout[(size_t)n * 128 + tid] = hf[tid];
}

// ================= skip-GRU input gemm (reads f16 Cc) =================
__global__ __launch_bounds__(256) void gis_k(const f16* __restrict__ cc, const float* __restrict__ wih,
                                             const float* __restrict__ bih, float* __restrict__ gi) {
  __shared__ float sx[24 * 128];
  int t = blockIdx.x, b = blockIdx.y;
  int tid = threadIdx.x;
  for (int idx = tid; idx < 24 * 128; idx += 256) {
    int sk = idx >> 7, i = idx & 127;
    int l = 19 + t * 24 + sk;
    sx[idx] = (float)cc[((size_t)l * Bn + b) * HIDCn + i];
  }
  __syncthreads();
  for (int idx = tid; idx < 576; idx += 256) {
    int sk = idx / 24, g = idx - sk * 24;
    float a = bih[g];
    for (int i = 0; i < 128; ++i) a = fmaf(sx[sk * 128 + i], wih[g * 128 + i], a);
    gi[((size_t)t * (Bn * SKIPn) + b * 24 + sk) * 24 + g] = a;
  }
}

// ================= skip-GRU recurrent =================
__global__ __launch_bounds__(256) void grus_k(const float* __restrict__ gi, const float* __restrict__ whh,
                                              const float* __restrict__ bhh, float* __restrict__ hout) {
  __shared__ float sw[24 * 8];
  __shared__ float sb[24];
  int tid = threadIdx.x;
  int n = blockIdx.x * 256 + tid;
  if (tid < 192) sw[tid] = whh[tid];
  if (tid < 24) sb[tid] = bhh[tid];
  __syncthreads();
  float h[8];
#pragma unroll
  for (int jj = 0; jj < 8; ++jj) h[jj] = 0.f;
  for (int t = 0; t < PTn; ++t) {
    const float* gir = gi + ((size_t)t * (Bn * SKIPn) + n) * 24;
    float gh[24];
#pragma unroll
    for (int g = 0; g < 24; ++g) {
      float a = sb[g];
#pragma unroll
      for (int jj = 0; jj < 8; ++jj) a = fmaf(sw[g * 8 + jj], h[jj], a);
      gh[g] = a;
    }
#pragma unroll
    for (int jj = 0; jj < 8; ++jj) {
      float rg = sigmf(gir[jj] + gh[jj]);
      float zg = sigmf(gir[8 + jj] + gh[8 + jj]);
      float ng = tanhf(gir[16 + jj] + rg * gh[16 + jj]);
      h[jj] = (1.f - zg) * ng + zg * h[jj];
    }
  }
#pragma unroll
  for (int jj = 0; jj < 8; ++jj) hout[(size_t)n * 8 + jj] = h[jj];
}

// ================= final linear + highway (reads f16 XRh) =================
__global__ __launch_bounds__(384) void final_k(const float* __restrict__ h1, const float* __restrict__ hsb,
                                               const float* __restrict__ lw, const float* __restrict__ lb,
                                               const f16* __restrict__ XRh, const float* __restrict__ hww,
                                               const float* __restrict__ hwb, float* __restrict__ out) {
  __shared__ float sr[320];
  __shared__ float shw[24];
  int b = blockIdx.x;
  int tid = threadIdx.x;
  if (tid < 128) sr[tid] = h1[(size_t)b * 128 + tid];
  else if (tid < 320) sr[tid] = hsb[(size_t)b * 192 + (tid - 128)];
  if (tid >= 320 && tid < 344) shw[tid - 320] = hww[tid - 320];
  __syncthreads();
  int m = tid;
  if (m >= Mn) return;
  float a = lb[m];
  const float* wr = lw + (size_t)m * 320;
  for (int c = 0; c < 320; ++c) a = fmaf(sr[c], wr[c], a);
  float z = hwb[0];
  const f16* xrr = XRh + ((size_t)b * Pn + (Pn - HWn)) * Mp + m;
#pragma unroll
  for (int k = 0; k < HWn; ++k) z = fmaf((float)xrr[(size_t)k * Mp], shw[k], z);
  out[(size_t)b * Mn + m] = a + z;
}

extern "C" void kernel_launch(void* const* d_in, const int* in_sizes, int n_in,
                              void* d_out, int out_size, void* d_ws, size_t ws_size,
                              hipStream_t stream) {
  const float* x = (const float*)d_in[0];
  const float* tw1 = (const float*)d_in[1];
  const float* tb1 = (const float*)d_in[2];
  const float* tw2 = (const float*)d_in[3];
  const float* tb2 = (const float*)d_in[4];
  const float* c1w = (const float*)d_in[5];
  const float* c1b = (const float*)d_in[6];
  const float* g1wih = (const float*)d_in[7];
  const float* g1whh = (const float*)d_in[8];
  const float* g1bih = (const float*)d_in[9];
  const float* g1bhh = (const float*)d_in[10];
  const float* gswih = (const float*)d_in[11];
  const float* gswhh = (const float*)d_in[12];
  const float* gsbih = (const float*)d_in[13];
  const float* gsbhh = (const float*)d_in[14];
  const float* l1w = (const float*)d_in[15];
  const float* l1b = (const float*)d_in[16];
  const float* hww = (const float*)d_in[17];
  const float* hwb = (const float*)d_in[18];
  float* out = (float*)d_out;

  // ---------- workspace plan (~218 MB) ----------
  const size_t Ah = 17891328ull, Bh = 17891328ull, Ch = 17203200ull;
  f16* Aq = (f16*)d_ws;
  f16* Bq = Aq + Ah;
  f16* Cq = Bq + Bh;
  f16* Wl1 = Cq + Ch;                       // 10,321,920 halves
  f16* Wl2 = Wl1 + 10321920ull;             // 6,193,152 halves
  f16* W2d = Wl2 + 6193152ull;              // 258,048 halves
  f16* Wih16 = W2d + 258048ull;             // 49,152 halves
  float* giA = (float*)(Wih16 + 49152ull);  // 18,382,848 floats
  float* h1 = giA + 18382848ull;
  float* hsb = h1 + (size_t)Bn * HIDRn;
  float* gis = hsb + (size_t)Bn * SKIPn * HIDSn;
  // post-tree aliases
  f16* XRh = Bq;                            // B*P*Mp = 16,515,072 halves
  f16* Cc = Cq;                             // L*B*128 = 6,125,568 halves

  f16* EO[3] = {Aq, Aq, Bq};
  f16* S1[3] = {Bq, Cq, Aq};
  f16* CD[3] = {Cq, Bq, Cq};
  f16* S3[3] = {Aq, Aq, Bq};
  f16* EU[3] = {Bq, Cq, Aq};
  const int WC0[3] = {0, 1, 2}, WC1[3] = {0, 3, 1}, WC2[3] = {0, 0, 1};

  repack_c1w<<<dim3(8, 126), 256, 0, stream>>>(c1w, W2d);
  repack_wih<<<dim3(192), 256, 0, stream>>>(g1wih, Wih16);

  for (int L = 0; L < 3; ++L) {
    int NL = 1 << L;
    int Th = 96 >> L;
    int Z = 2 * NL;
    long zsEO = (long)Bn * Th * Mp;
    long zsS1 = (long)Bn * (Th + 2) * Mp;
    repack_w<<<dim3(24, 5 * 21, NL * 4), 256, 0, stream>>>(tw1, Wl1, 5, WC0[L], WC1[L], WC2[L]);
    repack_w<<<dim3(24, 3 * 21, NL * 4), 256, 0, stream>>>(tw2, Wl2, 3, WC0[L], WC1[L], WC2[L]);
    if (L == 0)
      deint_k<<<dim3(Bn, Th, 2), 256, 0, stream>>>(x, nullptr, 0, EO[0], Th);
    else
      deint_k<<<dim3(Bn, Th, Z), 256, 0, stream>>>(nullptr, EU[L - 1], 2 * Th, EO[L], Th);
    int ty1 = (Th + 2 + 31) / 32, ty2 = (Th + 31) / 32;
    conv_mfma<5, 0><<<dim3(Bn / 2, ty1, Z), 256, 0, stream>>>(
        EO[L], zsEO, Th, Wl1, WC0[L], WC1[L], WC2[L], 0, tb1,
        nullptr, 0, S1[L], zsS1, Th + 2);
    conv_mfma<3, 1><<<dim3(Bn / 2, ty2, Z), 256, 0, stream>>>(
        S1[L], zsS1, Th + 2, Wl2, WC0[L], WC1[L], WC2[L], 0, tb2,
        EO[L], zsEO, CD[L], zsEO, Th);
    conv_mfma<5, 0><<<dim3(Bn / 2, ty1, Z), 256, 0, stream>>>(
        CD[L], zsEO, Th, Wl1, WC0[L], WC1[L], WC2[L], 2, tb1,
        nullptr, 0, S3[L], zsS1, Th + 2);
    conv_mfma<3, 2><<<dim3(Bn / 2, ty2, Z), 256, 0, stream>>>(
        S3[L], zsS1, Th + 2, Wl2, WC0[L], WC1[L], WC2[L], 2, tb2,
        CD[L], zsEO, EU[L], zsEO, Th);
  }

  combine_k<<<dim3(Bn, Pn), 256, 0, stream>>>(x, EU[2], XRh);

  conv2d_mfma<<<dim3(Bn / 2, 6), 256, 0, stream>>>(XRh, W2d, c1b, Cc);
  gemm_gi_mfma<<<dim3((Ln * Bn) / 64), 256, 0, stream>>>(Cc, Wih16, g1bih, giA);
  gru1_k<<<dim3(Bn), 384, 0, stream>>>(giA, g1whh, g1bhh, h1);
  gis_k<<<dim3(PTn, Bn), 256, 0, stream>>>(Cc, gswih, gsbih, gis);
  grus_k<<<dim3((Bn * SKIPn) / 256), 256, 0, stream>>>(gis, gswhh, gsbhh, hsb);
  final_k<<<dim3(Bn), 384, 0, stream>>>(h1, hsb, l1w, l1b, XRh, hww, hwb, out);
}